// Round 6
// baseline (791.710 us; speedup 1.0000x reference)
//
#include <hip/hip_runtime.h>
#include <cstdint>
#include <cstddef>

#define NN 20000
#define NE 320000

typedef float f32x4 __attribute__((ext_vector_type(4)));
typedef short s16x8 __attribute__((ext_vector_type(8)));
typedef unsigned short us;

struct KBd { const us* p; int rs; int cs; };   // strides in shorts
struct KB10 { KBd b[10]; };

__device__ __forceinline__ us f2bf(float x){
    unsigned u = __float_as_uint(x);
    unsigned r = (u + 0x7fffu + ((u >> 16) & 1u)) >> 16;
    return (us)r;
}
__device__ __forceinline__ float bf2f(us s){
    return __uint_as_float(((unsigned)s) << 16);
}

__device__ __forceinline__ void gl16(const void* g, void* l){
    __builtin_amdgcn_global_load_lds((const __attribute__((address_space(1))) unsigned int*)g,
                                     (__attribute__((address_space(3))) unsigned int*)l, 16, 0, 0);
}

__device__ __forceinline__ void upd8(uint4 v, float w, float* ao, float* ai){
    float f0=__uint_as_float(v.x<<16), f1=__uint_as_float(v.x&0xffff0000u);
    float f2=__uint_as_float(v.y<<16), f3=__uint_as_float(v.y&0xffff0000u);
    float f4=__uint_as_float(v.z<<16), f5=__uint_as_float(v.z&0xffff0000u);
    float f6=__uint_as_float(v.w<<16), f7=__uint_as_float(v.w&0xffff0000u);
    ao[0]=fmaf(w,f0,ao[0]); ao[1]=fmaf(w,f1,ao[1]); ao[2]=fmaf(w,f2,ao[2]); ao[3]=fmaf(w,f3,ao[3]);
    ao[4]=fmaf(w,f4,ao[4]); ao[5]=fmaf(w,f5,ao[5]); ao[6]=fmaf(w,f6,ao[6]); ao[7]=fmaf(w,f7,ao[7]);
    ai[0]+=f0; ai[1]+=f1; ai[2]+=f2; ai[3]+=f3; ai[4]+=f4; ai[5]+=f5; ai[6]+=f6; ai[7]+=f7;
}
__device__ __forceinline__ void updw(uint4 v, float w, float* a){
    float f0=__uint_as_float(v.x<<16), f1=__uint_as_float(v.x&0xffff0000u);
    float f2=__uint_as_float(v.y<<16), f3=__uint_as_float(v.y&0xffff0000u);
    float f4=__uint_as_float(v.z<<16), f5=__uint_as_float(v.z&0xffff0000u);
    float f6=__uint_as_float(v.w<<16), f7=__uint_as_float(v.w&0xffff0000u);
    a[0]=fmaf(w,f0,a[0]); a[1]=fmaf(w,f1,a[1]); a[2]=fmaf(w,f2,a[2]); a[3]=fmaf(w,f3,a[3]);
    a[4]=fmaf(w,f4,a[4]); a[5]=fmaf(w,f5,a[5]); a[6]=fmaf(w,f6,a[6]); a[7]=fmaf(w,f7,a[7]);
}
__device__ __forceinline__ uint4 pack8(const float* a){
    uint4 r;
    r.x=((unsigned)f2bf(a[1])<<16)|f2bf(a[0]);
    r.y=((unsigned)f2bf(a[3])<<16)|f2bf(a[2]);
    r.z=((unsigned)f2bf(a[5])<<16)|f2bf(a[4]);
    r.w=((unsigned)f2bf(a[7])<<16)|f2bf(a[6]);
    return r;
}
__device__ __forceinline__ uint4 pack8s(const float* a, float s){
    uint4 r;
    r.x=((unsigned)f2bf(s*a[1])<<16)|f2bf(s*a[0]);
    r.y=((unsigned)f2bf(s*a[3])<<16)|f2bf(s*a[2]);
    r.z=((unsigned)f2bf(s*a[5])<<16)|f2bf(s*a[4]);
    r.w=((unsigned)f2bf(s*a[7])<<16)|f2bf(s*a[6]);
    return r;
}

// ---------------- init / graph ----------------

__global__ void k_zero(uint32_t* p, int n){
    int i = blockIdx.x*256 + threadIdx.x;
    if(i < n) p[i] = 0u;
}

__global__ void k_degree(const int* __restrict__ ei, int* degout, int* degin){
    int e = blockIdx.x*256 + threadIdx.x;
    if(e < NE){
        atomicAdd(&degout[ei[e]], 1);
        atomicAdd(&degin[ei[NE+e]], 1);
    }
}

__global__ void k_scan(const int* __restrict__ degin, int* __restrict__ coloff,
                       float* __restrict__ invdegin){
    __shared__ int part[1024];
    int t = threadIdx.x;
    int base = t*20;
    int s = 0;
    for(int k=0;k<20;k++){ int i = base+k; if(i < NN) s += degin[i]; }
    part[t] = s;
    __syncthreads();
    for(int off=1; off<1024; off<<=1){
        int v = (t>=off) ? part[t-off] : 0;
        __syncthreads();
        part[t] += v;
        __syncthreads();
    }
    int run = (t>0) ? part[t-1] : 0;
    for(int k=0;k<20;k++){
        int i = base+k;
        if(i < NN){
            int d = degin[i];
            coloff[i] = run;
            run += d;
            invdegin[i] = (d>0) ? (1.0f/(float)d) : 0.0f;
        }
    }
    if(t==1023) coloff[NN] = part[1023];
}

__global__ void k_csr(const int* __restrict__ ei, const int* __restrict__ degout,
                      const int* __restrict__ coloff, int* cnt, int2* __restrict__ ew){
    int e = blockIdx.x*256 + threadIdx.x;
    if(e < NE){
        int r = ei[e], c = ei[NE+e];
        int pos = coloff[c] + atomicAdd(&cnt[c], 1);
        int2 v; v.x = r; v.y = __float_as_int(1.0f/(float)degout[r]);
        ew[pos] = v;
    }
}

// ---------------- CNN embedding ----------------

__global__ void k_conv1(const float* __restrict__ x, const float* __restrict__ w1,
                        const float* __restrict__ b1, us* __restrict__ y1b){
    __shared__ float w[320];
    __shared__ float bb[32];
    int t = threadIdx.x;
    for(int i=t;i<320;i+=256) w[i] = w1[i];
    if(t < 32) bb[t] = b1[t];
    __syncthreads();
    int gid = blockIdx.x*256 + t;
    if(gid >= NN*31) return;
    int node = gid/31, p = gid - node*31;
    const float* xr = x + node*100 + 3*p;
    float xv[10];
    #pragma unroll
    for(int k=0;k<10;k++) xv[k] = xr[k];
    us* yo = y1b + (size_t)node*1024 + p;
    #pragma unroll
    for(int c=0;c<32;c++){
        float a = bb[c];
        #pragma unroll
        for(int k=0;k<10;k++) a = fmaf(w[c*10+k], xv[k], a);
        yo[c*32] = f2bf(fmaxf(a, 0.0f));
    }
    if(p == 0){
        #pragma unroll
        for(int c=0;c<32;c++) y1b[(size_t)node*1024 + c*32 + 31] = 0;
    }
}

template<int SLOTS, int PPC>
__global__ void k_chanstats_bf(const us* __restrict__ y, float* __restrict__ sq){
    int tid = blockIdx.x*blockDim.x + threadIdx.x;
    int slot = tid & (SLOTS-1);
    int node0 = tid / SLOTS;
    int nstride = (gridDim.x*blockDim.x) / SLOTS;
    int c = slot / PPC;
    float s = 0.f, q = 0.f;
    for(int n=node0; n<NN; n+=nstride){
        float v = bf2f(y[(size_t)n*SLOTS + slot]);
        s += v; q = fmaf(v, v, q);
    }
    #pragma unroll
    for(int m=PPC>>1; m>0; m>>=1){
        s += __shfl_xor(s, m);
        q += __shfl_xor(q, m);
    }
    if((threadIdx.x & (PPC-1)) == 0){
        atomicAdd(&sq[c], s);
        atomicAdd(&sq[32+c], q);
    }
}

__global__ void k_bnfin(const float* __restrict__ sq, const float* __restrict__ gamma,
                        const float* __restrict__ beta, float* __restrict__ scsh,
                        float inv_count){
    int c = threadIdx.x;
    if(c < 32){
        float m = sq[c]*inv_count;
        float v = sq[32+c]*inv_count - m*m;
        float sc = gamma[c]*rsqrtf(v + 1e-5f);
        scsh[c] = sc;
        scsh[32+c] = beta[c] - m*sc;
    }
}

// conv2: 8 nodes/block, thread=(node_local, c2), register-blocked
__global__ void __launch_bounds__(256) k_conv2(const us* __restrict__ y1b,
                        const float* __restrict__ w2, const float* __restrict__ b2,
                        const float* __restrict__ scsh1, us* __restrict__ Xpre){
    __shared__ float wlds[10240];   // [c*10+k]*32 + c2
    __shared__ float hlds[8*1040];  // [nl]*1040 + c*32 + p
    int t = threadIdx.x;
    int node0 = blockIdx.x*8;
    #pragma unroll
    for(int j=0;j<40;j++){
        int idx = j*256 + t;
        int ck = idx>>5, c2 = idx&31;
        wlds[ck*32 + c2] = w2[c2*320 + ck];
    }
    #pragma unroll
    for(int j=0;j<32;j++){
        int idx = j*256 + t;
        int nl = idx>>10, i = idx&1023;
        int c = i>>5;
        hlds[nl*1040 + i] = fmaf(scsh1[c], bf2f(y1b[(size_t)(node0+nl)*1024 + i]), scsh1[32+c]);
    }
    __syncthreads();
    int nl = t>>5, c2 = t&31;
    int hbase = nl*1040;
    float acc[8];
    float b = b2[c2];
    #pragma unroll
    for(int p=0;p<8;p++) acc[p] = b;
    for(int c=0;c<32;c++){
        float wr[10];
        #pragma unroll
        for(int k=0;k<10;k++) wr[k] = wlds[(c*10+k)*32 + c2];
        float hv[32];
        #pragma unroll
        for(int q=0;q<8;q++){
            float4 v = *(const float4*)&hlds[hbase + c*32 + q*4];
            hv[q*4+0]=v.x; hv[q*4+1]=v.y; hv[q*4+2]=v.z; hv[q*4+3]=v.w;
        }
        #pragma unroll
        for(int p=0;p<8;p++){
            #pragma unroll
            for(int k=0;k<10;k++)
                acc[p] = fmaf(wr[k], hv[3*p+k], acc[p]);
        }
    }
    uint4 pk;
    pk.x = ((unsigned)f2bf(fmaxf(acc[1],0.f))<<16) | f2bf(fmaxf(acc[0],0.f));
    pk.y = ((unsigned)f2bf(fmaxf(acc[3],0.f))<<16) | f2bf(fmaxf(acc[2],0.f));
    pk.z = ((unsigned)f2bf(fmaxf(acc[5],0.f))<<16) | f2bf(fmaxf(acc[4],0.f));
    pk.w = ((unsigned)f2bf(fmaxf(acc[7],0.f))<<16) | f2bf(fmaxf(acc[6],0.f));
    *(uint4*)&Xpre[(size_t)(node0+nl)*256 + c2*8] = pk;
}

// build XHp [node][512]: groups g: shorts g*16..+7 = BN2(X)[g*8..], +8..+15 = h0[g*8..]
__global__ void __launch_bounds__(256) k_prep(const us* __restrict__ Xpre,
        const float* __restrict__ scsh, const float* __restrict__ h0,
        us* __restrict__ XHp){
    int node = blockIdx.x*4 + (threadIdx.x>>6);
    if(node >= NN) return;
    int lane = threadIdx.x & 63;
    int half = lane>>5, g = lane&31;
    uint4 o;
    if(half == 0){
        uint4 v = *(const uint4*)(Xpre + (size_t)node*256 + g*8);
        float sc = scsh[g], sh = scsh[32+g];
        float y[8];
        y[0]=fmaf(sc,__uint_as_float(v.x<<16),sh); y[1]=fmaf(sc,__uint_as_float(v.x&0xffff0000u),sh);
        y[2]=fmaf(sc,__uint_as_float(v.y<<16),sh); y[3]=fmaf(sc,__uint_as_float(v.y&0xffff0000u),sh);
        y[4]=fmaf(sc,__uint_as_float(v.z<<16),sh); y[5]=fmaf(sc,__uint_as_float(v.z&0xffff0000u),sh);
        y[6]=fmaf(sc,__uint_as_float(v.w<<16),sh); y[7]=fmaf(sc,__uint_as_float(v.w&0xffff0000u),sh);
        o = pack8(y);
    }else{
        float4 a = *(const float4*)(h0 + (size_t)node*256 + g*8);
        float4 b = *(const float4*)(h0 + (size_t)node*256 + g*8 + 4);
        float y[8] = {a.x,a.y,a.z,a.w,b.x,b.y,b.z,b.w};
        o = pack8(y);
    }
    *(uint4*)(XHp + (size_t)node*512 + (size_t)g*16 + half*8) = o;
}

// ---------------- effective weights (transposed, bf16) ----------------
// term: 0:W00+W10-W02-W12 1:W01 2:W11 3:2*W02 4:2*W12

__device__ __forceinline__ float weff_val(const float* W, int term, size_t base){
    const size_t S = 512*256;
    if(term==0)      return W[0*S+base] + W[3*S+base] - W[2*S+base] - W[5*S+base];
    else if(term==1) return W[1*S+base];
    else if(term==2) return W[4*S+base];
    else if(term==3) return 2.0f*W[2*S+base];
    else             return 2.0f*W[5*S+base];
}

__global__ void k_weff_zr_t(const float* __restrict__ Wz, const float* __restrict__ Wr,
                            us* __restrict__ Wt){
    int k = blockIdx.x*256 + threadIdx.x;
    int col = blockIdx.y;
    const float* W = (col < 256) ? Wz : Wr;
    int j = col & 255;
    int kb = k >> 8, rr = k & 255;
    size_t base = (size_t)((kb & 1)*256 + rr)*256 + j;
    Wt[(size_t)col*2560 + k] = f2bf(weff_val(W, kb>>1, base));
}

__global__ void k_weff_h_t(const float* __restrict__ Wh, us* __restrict__ Wt){
    int k = blockIdx.x*256 + threadIdx.x;
    int col = blockIdx.y;
    int kb = k >> 8, rr = k & 255;
    size_t base = (size_t)((kb & 1)*256 + rr)*256 + col;
    Wt[(size_t)col*2560 + k] = f2bf(weff_val(Wh, kb>>1, base));
}

// ---------------- propagation (pair-interleaved uint4 gathers) ----------------
// lane<32 handles first logical array's cols g*8.., lane>=32 second's.

__global__ void __launch_bounds__(256) k_prop1(const us* __restrict__ XHp,
        const int* __restrict__ coloff, const int2* __restrict__ ew,
        const float* __restrict__ invdeg, us* __restrict__ T1op, us* __restrict__ T1ip){
    int node = blockIdx.x*4 + (threadIdx.x>>6);
    if(node >= NN) return;
    int lane = threadIdx.x & 63;
    size_t lo = (size_t)(lane&31)*16 + (lane>>5)*8;
    int s = coloff[node], e = coloff[node+1];
    float ao[8]={0,0,0,0,0,0,0,0}, ai[8]={0,0,0,0,0,0,0,0};
    int j = s;
    for(; j+3 < e; j += 4){
        int2 e0=ew[j], e1=ew[j+1], e2=ew[j+2], e3=ew[j+3];
        uint4 v0=*(const uint4*)(XHp+(size_t)e0.x*512+lo);
        uint4 v1=*(const uint4*)(XHp+(size_t)e1.x*512+lo);
        uint4 v2=*(const uint4*)(XHp+(size_t)e2.x*512+lo);
        uint4 v3=*(const uint4*)(XHp+(size_t)e3.x*512+lo);
        upd8(v0,__int_as_float(e0.y),ao,ai);
        upd8(v1,__int_as_float(e1.y),ao,ai);
        upd8(v2,__int_as_float(e2.y),ao,ai);
        upd8(v3,__int_as_float(e3.y),ao,ai);
    }
    for(; j < e; j++){
        int2 ed = ew[j];
        uint4 v = *(const uint4*)(XHp+(size_t)ed.x*512+lo);
        upd8(v,__int_as_float(ed.y),ao,ai);
    }
    float wi = invdeg[node];
    *(uint4*)(T1op+(size_t)node*512+lo) = pack8(ao);
    *(uint4*)(T1ip+(size_t)node*512+lo) = pack8s(ai,wi);
}

__global__ void __launch_bounds__(256) k_prop2(const us* __restrict__ T1op,
        const us* __restrict__ T1ip,
        const int* __restrict__ coloff, const int2* __restrict__ ew,
        const float* __restrict__ invdeg, us* __restrict__ P2op, us* __restrict__ P2ip){
    int node = blockIdx.x*4 + (threadIdx.x>>6);
    if(node >= NN) return;
    int lane = threadIdx.x & 63;
    size_t lo = (size_t)(lane&31)*16 + (lane>>5)*8;
    int s = coloff[node], e = coloff[node+1];
    float ao[8]={0,0,0,0,0,0,0,0}, ai[8]={0,0,0,0,0,0,0,0};
    int j = s;
    for(; j+1 < e; j += 2){
        int2 e0=ew[j], e1=ew[j+1];
        size_t o0=(size_t)e0.x*512+lo, o1=(size_t)e1.x*512+lo;
        uint4 a0=*(const uint4*)(T1op+o0), b0=*(const uint4*)(T1ip+o0);
        uint4 a1=*(const uint4*)(T1op+o1), b1=*(const uint4*)(T1ip+o1);
        float one = 1.0f;
        updw(a0,__int_as_float(e0.y),ao); updw(b0,one,ai);
        updw(a1,__int_as_float(e1.y),ao); updw(b1,one,ai);
    }
    if(j < e){
        int2 ed = ew[j];
        size_t o0=(size_t)ed.x*512+lo;
        uint4 a0=*(const uint4*)(T1op+o0), b0=*(const uint4*)(T1ip+o0);
        updw(a0,__int_as_float(ed.y),ao); updw(b0,1.0f,ai);
    }
    float wi = invdeg[node];
    *(uint4*)(P2op+(size_t)node*512+lo) = pack8(ao);
    *(uint4*)(P2ip+(size_t)node*512+lo) = pack8s(ai,wi);
}

// q1: prop of RH [node][256]; halves process alternate edges, combine via shfl.
__global__ void __launch_bounds__(256) k_propq1(const us* __restrict__ RHb,
        const int* __restrict__ coloff, const int2* __restrict__ ew,
        const float* __restrict__ invdeg, us* __restrict__ Q1p){
    int node = blockIdx.x*4 + (threadIdx.x>>6);
    if(node >= NN) return;
    int lane = threadIdx.x & 63;
    int half = lane>>5, g = lane&31;
    int s = coloff[node], e = coloff[node+1];
    float ao[8]={0,0,0,0,0,0,0,0}, ai[8]={0,0,0,0,0,0,0,0};
    int j = s;
    for(; j+1 < e; j += 2){
        int2 ed = ew[j+half];
        uint4 v = *(const uint4*)(RHb+(size_t)ed.x*256+g*8);
        upd8(v,__int_as_float(ed.y),ao,ai);
    }
    if(j < e && half == 0){
        int2 ed = ew[j];
        uint4 v = *(const uint4*)(RHb+(size_t)ed.x*256+g*8);
        upd8(v,__int_as_float(ed.y),ao,ai);
    }
    #pragma unroll
    for(int k=0;k<8;k++){
        ao[k] += __shfl_xor(ao[k],32);
        ai[k] += __shfl_xor(ai[k],32);
    }
    if(half == 0){
        float wi = invdeg[node];
        *(uint4*)(Q1p+(size_t)node*512+(size_t)g*16)   = pack8(ao);
        *(uint4*)(Q1p+(size_t)node*512+(size_t)g*16+8) = pack8s(ai,wi);
    }
}

// q2: prop of Q1p (o-half weighted -> Q2o, i-half plain -> Q2i), one uint4/edge/lane.
__global__ void __launch_bounds__(256) k_propq2(const us* __restrict__ Q1p,
        const int* __restrict__ coloff, const int2* __restrict__ ew,
        const float* __restrict__ invdeg, us* __restrict__ Q2p){
    int node = blockIdx.x*4 + (threadIdx.x>>6);
    if(node >= NN) return;
    int lane = threadIdx.x & 63;
    int half = lane>>5;
    size_t lo = (size_t)(lane&31)*16 + half*8;
    int s = coloff[node], e = coloff[node+1];
    float a[8]={0,0,0,0,0,0,0,0};
    int j = s;
    for(; j+3 < e; j += 4){
        int2 e0=ew[j], e1=ew[j+1], e2=ew[j+2], e3=ew[j+3];
        uint4 v0=*(const uint4*)(Q1p+(size_t)e0.x*512+lo);
        uint4 v1=*(const uint4*)(Q1p+(size_t)e1.x*512+lo);
        uint4 v2=*(const uint4*)(Q1p+(size_t)e2.x*512+lo);
        uint4 v3=*(const uint4*)(Q1p+(size_t)e3.x*512+lo);
        updw(v0, half ? 1.0f : __int_as_float(e0.y), a);
        updw(v1, half ? 1.0f : __int_as_float(e1.y), a);
        updw(v2, half ? 1.0f : __int_as_float(e2.y), a);
        updw(v3, half ? 1.0f : __int_as_float(e3.y), a);
    }
    for(; j < e; j++){
        int2 ed = ew[j];
        uint4 v = *(const uint4*)(Q1p+(size_t)ed.x*512+lo);
        updw(v, half ? 1.0f : __int_as_float(ed.y), a);
    }
    float sc = half ? invdeg[node] : 1.0f;
    *(uint4*)(Q2p+(size_t)node*512+lo) = pack8s(a,sc);
}

// ---------------- bf16 MFMA GEMM, 2-phase double-buffer, XCD affinity ----------------

template<int MODE, int BNT>
__global__ void __launch_bounds__(256) k_gemm(KB10 blocks, const us* __restrict__ Wt,
        const float* __restrict__ bias0, const float* __restrict__ bias1,
        const float* __restrict__ h0, const float* __restrict__ Zin,
        float* __restrict__ out0, us* __restrict__ out1){
    constexpr int WN = BNT/32;
    constexpr int NB = BNT/64;        // B staging issues per thread
    __shared__ us As[2][4096];
    __shared__ us Bs[2][BNT*32];
    int t = threadIdx.x;
    int wid = t >> 6, lane = t & 63;
    int l15 = lane & 15, kg = lane >> 4;

    int bid = blockIdx.x;
    int xcd = bid & 7, sblk = bid >> 3;
    int cidx = sblk & 3, r = (sblk >> 2)*8 + xcd;
    if(r >= 157) return;
    int row0 = r*128, col0 = cidx*BNT;
    int rowbase = (wid >> 1)*64, colbase = (wid & 1)*(BNT/2);
    int swz = (l15 >> 1) & 3;

    int srA[2], sgA[2], graA[2];
    #pragma unroll
    for(int i=0;i<2;i++){
        int c = t + i*256;
        srA[i] = c >> 2;
        sgA[i] = (c & 3) ^ ((srA[i] >> 1) & 3);
        int gr = row0 + srA[i];
        graA[i] = (gr < NN) ? gr : NN-1;
    }
    int srB[NB], sgB[NB];
    #pragma unroll
    for(int i=0;i<NB;i++){
        int c = t + i*256;
        srB[i] = c >> 2;
        sgB[i] = (c & 3) ^ ((srB[i] >> 1) & 3);
    }

    f32x4 acc[4][WN] = {};

    auto stage = [&](int buf, int step){
        int kb = step >> 3, kt = (step & 7)*32, ktc = (step & 7)*4;
        const us* Ap = blocks.b[kb].p;
        int rs = blocks.b[kb].rs, cs = blocks.b[kb].cs;
        #pragma unroll
        for(int i=0;i<2;i++)
            gl16(Ap + (size_t)graA[i]*rs + (size_t)(ktc + sgA[i])*cs, &As[buf][(t+i*256)*8]);
        const us* Wp = Wt + (size_t)kb*256;
        #pragma unroll
        for(int i=0;i<NB;i++)
            gl16(Wp + (size_t)(col0+srB[i])*2560 + kt + sgB[i]*8, &Bs[buf][(t+i*256)*8]);
    };

    stage(0, 0);
    __syncthreads();
    int cur = 0;
    for(int step=0; step<80; step++){
        if(step < 79) stage(cur^1, step+1);
        s16x8 af[4], bfr[WN];
        #pragma unroll
        for(int i=0;i<4;i++){
            int row = rowbase + i*16 + l15;
            af[i] = *(const s16x8*)&As[cur][(row*4 + (kg ^ swz))*8];
        }
        #pragma unroll
        for(int n=0;n<WN;n++){
            int colr = colbase + n*16 + l15;
            bfr[n] = *(const s16x8*)&Bs[cur][(colr*4 + (kg ^ swz))*8];
        }
        #pragma unroll
        for(int mi=0;mi<4;mi++){
            #pragma unroll
            for(int ni=0;ni<WN;ni++){
                acc[mi][ni] = __builtin_amdgcn_mfma_f32_16x16x32_bf16(
                    af[mi], bfr[ni], acc[mi][ni], 0, 0, 0);
            }
        }
        __syncthreads();
        cur ^= 1;
    }

    #pragma unroll
    for(int mi=0;mi<4;mi++){
        int gr0 = row0 + rowbase + mi*16 + kg*4;
        #pragma unroll
        for(int ni=0;ni<WN;ni++){
            int j = col0 + colbase + ni*16 + l15;
            #pragma unroll
            for(int rr=0;rr<4;rr++){
                int gr = gr0 + rr;
                if(gr < NN){
                    float a = acc[mi][ni][rr];
                    if(MODE == 0){
                        if(j < 256){
                            out0[(size_t)gr*256 + j] = 1.0f/(1.0f + expf(-(a + bias0[j])));
                        }else{
                            int jj = j - 256;
                            float rv = 1.0f/(1.0f + expf(-(a + bias1[jj])));
                            out1[(size_t)gr*256 + jj] = f2bf(rv * h0[(size_t)gr*256 + jj]);
                        }
                    }else{
                        float z = Zin[(size_t)gr*256 + j];
                        float ht = tanhf(a + bias0[j]);
                        float H = z*h0[(size_t)gr*256 + j] + (1.0f - z)*ht;
                        out0[(size_t)gr*256 + j] = fmaxf(H, 0.0f);
                    }
                }
            }
        }
    }
}

// ---------------- host ----------------

extern "C" void kernel_launch(void* const* d_in, const int* in_sizes, int n_in,
                              void* d_out, int out_size, void* d_ws, size_t ws_size,
                              hipStream_t stream){
    const float* x   = (const float*)d_in[0];
    const int*   ei  = (const int*)  d_in[1];
    const float* h0  = (const float*)d_in[2];
    const float* w1  = (const float*)d_in[3];
    const float* b1  = (const float*)d_in[4];
    const float* g1  = (const float*)d_in[5];
    const float* be1 = (const float*)d_in[6];
    const float* w2  = (const float*)d_in[7];
    const float* b2  = (const float*)d_in[8];
    const float* g2  = (const float*)d_in[9];
    const float* be2 = (const float*)d_in[10];
    const float* Wz  = (const float*)d_in[11];
    const float* bz  = (const float*)d_in[12];
    const float* Wr  = (const float*)d_in[13];
    const float* br  = (const float*)d_in[14];
    const float* Wh  = (const float*)d_in[15];
    const float* bh  = (const float*)d_in[16];
    float* out = (float*)d_out;
    float* wsf = (float*)d_ws;
    (void)in_sizes; (void)n_in; (void)out_size;

    // word (4B) offsets
    const size_t O_DEGO=0, O_DEGI=20000, O_CNT=40000, O_BN=60000;      // zero: 60256
    const size_t O_COLOFF=60288, O_EW=80384, O_INVDEG=720384;
    const size_t O_WTZR=740480, O_WTH=1395840;
    const size_t O_XPRE=1723520;
    const size_t O_XHP=4283520;
    const size_t O_T1OP=9403520, O_T1IP=14523520, O_P2OP=19643520, O_P2IP=24763520;
    const size_t O_Q1P=29883520, O_Q2P=35003520;
    const size_t O_RH=40123520, O_Z=42683520;
    const size_t WS_NEED_BYTES = (size_t)47803520 * 4;   // ~191 MB
    if(ws_size < WS_NEED_BYTES) return;

    int* degout = (int*)(wsf + O_DEGO);
    int* degin  = (int*)(wsf + O_DEGI);
    int* cnt    = (int*)(wsf + O_CNT);
    float* bn   = wsf + O_BN;
    int* coloff = (int*)(wsf + O_COLOFF);
    int2* ew    = (int2*)(wsf + O_EW);
    float* invdeg = wsf + O_INVDEG;
    us* Wtzr = (us*)(wsf + O_WTZR);
    us* Wth  = (us*)(wsf + O_WTH);
    us* Xpre = (us*)(wsf + O_XPRE);
    us* XHp  = (us*)(wsf + O_XHP);
    us* T1op = (us*)(wsf + O_T1OP);
    us* T1ip = (us*)(wsf + O_T1IP);
    us* P2op = (us*)(wsf + O_P2OP);
    us* P2ip = (us*)(wsf + O_P2IP);
    us* Q1p  = (us*)(wsf + O_Q1P);
    us* Q2p  = (us*)(wsf + O_Q2P);
    us* RHb  = (us*)(wsf + O_RH);
    float* Z = wsf + O_Z;
    us* y1b  = (us*)(wsf + O_T1OP);   // 20.48M shorts = T1OP..T1IP span, dead during CNN

    // graph CSR
    k_zero<<<236,256,0,stream>>>((uint32_t*)(wsf + O_DEGO), 60256);
    k_degree<<<1250,256,0,stream>>>(ei, degout, degin);
    k_scan<<<1,1024,0,stream>>>(degin, coloff, invdeg);
    k_csr<<<1250,256,0,stream>>>(ei, degout, coloff, cnt, ew);

    // CNN embedding
    k_conv1<<<2422,256,0,stream>>>(x, w1, b1, y1b);
    k_chanstats_bf<1024,32><<<256,256,0,stream>>>(y1b, bn+0);
    k_bnfin<<<1,32,0,stream>>>(bn+0, g1, be1, bn+64, 1.0f/620000.0f);
    k_conv2<<<2500,256,0,stream>>>(y1b, w2, b2, bn+64, Xpre);
    k_chanstats_bf<256,8><<<64,256,0,stream>>>(Xpre, bn+128);
    k_bnfin<<<1,32,0,stream>>>(bn+128, g2, be2, bn+192, 1.0f/160000.0f);
    k_prep<<<5000,256,0,stream>>>(Xpre, bn+192, h0, XHp);

    // effective weights (transposed bf16)
    k_weff_zr_t<<<dim3(10,512),256,0,stream>>>(Wz, Wr, Wtzr);
    k_weff_h_t<<<dim3(10,256),256,0,stream>>>(Wh, Wth);

    // hop1 + hop2 props (pair-interleaved)
    k_prop1<<<5000,256,0,stream>>>(XHp, coloff, ew, invdeg, T1op, T1ip);
    k_prop2<<<5000,256,0,stream>>>(T1op, T1ip, coloff, ew, invdeg, P2op, P2ip);

    // Z,R GEMM (fused sigmoid; RH = bf16(sigmoid(r)*h0))
    KB10 bzr = {{ {XHp,512,16},{XHp+8,512,16},{T1op,512,16},{T1op+8,512,16},
                  {T1ip,512,16},{T1ip+8,512,16},{P2op,512,16},{P2op+8,512,16},
                  {P2ip,512,16},{P2ip+8,512,16} }};
    k_gemm<0,128><<<640,256,0,stream>>>(bzr, Wtzr, bz, br, h0, nullptr, Z, RHb);

    // props of RH
    k_propq1<<<5000,256,0,stream>>>(RHb, coloff, ew, invdeg, Q1p);
    k_propq2<<<5000,256,0,stream>>>(Q1p, coloff, ew, invdeg, Q2p);

    // H~ GEMM (fused tanh + gate + relu -> out)
    KB10 bhh = {{ {XHp,512,16},{RHb,256,8},{T1op,512,16},{Q1p,512,16},
                  {T1ip,512,16},{Q1p+8,512,16},{P2op,512,16},{Q2p,512,16},
                  {P2ip,512,16},{Q2p+8,512,16} }};
    k_gemm<1,64><<<640,256,0,stream>>>(bhh, Wth, bh, nullptr, h0, Z, out, nullptr);
}